// Round 1
// baseline (451.474 us; speedup 1.0000x reference)
//
#include <hip/hip_runtime.h>
#include <stdint.h>

typedef short bf16x8 __attribute__((ext_vector_type(8)));
typedef float f32x4 __attribute__((ext_vector_type(4)));

#define B_   512
#define N_   256
#define C_   192
#define H_   6
#define D_   32
#define NW_  64

__device__ __forceinline__ uint16_t f2bf(float f) {
    uint32_t u = __builtin_bit_cast(uint32_t, f);
    u += 0x7FFFu + ((u >> 16) & 1u);
    return (uint16_t)(u >> 16);
}

__device__ __forceinline__ bf16x8 ld_bf8(const uint16_t* p) {
    uint4 u = *reinterpret_cast<const uint4*>(p);
    return __builtin_bit_cast(bf16x8, u);
}

// ---------------- prep: mask -> AND-selector, weights -> bf16 ----------------
__global__ void prep_kernel(const float* __restrict__ mask,
                            const float* __restrict__ wqkv,
                            const float* __restrict__ wproj,
                            uint16_t* __restrict__ sel,
                            uint16_t* __restrict__ wqkv_bf,
                            uint16_t* __restrict__ wproj_bf) {
    const int64_t NSEL = (int64_t)NW_ * N_ * N_;       // 4194304
    const int64_t NWQ  = 3 * C_ * C_;                  // 110592
    const int64_t NWP  = (int64_t)C_ * C_;             // 36864
    int64_t i = (int64_t)blockIdx.x * blockDim.x + threadIdx.x;
    int64_t stride = (int64_t)gridDim.x * blockDim.x;
    for (; i < NSEL + NWQ + NWP; i += stride) {
        if (i < NSEL) {
            sel[i] = (mask[i] == 0.0f) ? 0xFFFFu : 0u;   // exp(0)=1, exp(-inf)=0
        } else if (i < NSEL + NWQ) {
            int64_t j = i - NSEL;
            wqkv_bf[j] = f2bf(wqkv[j]);
        } else {
            int64_t j = i - NSEL - NWQ;
            wproj_bf[j] = f2bf(wproj[j]);
        }
    }
}

// ---------------- kernel A: qkv = x @ Wqkv^T, scatter to q,k,vT (bf16) ------
// grid (1024, 3)  block 512.  blockIdx.y: 0=q, 1=k, 2=v
__global__ __launch_bounds__(512, 2)
void qkv_kernel(const float* __restrict__ x, const uint16_t* __restrict__ wq,
                uint16_t* __restrict__ qbuf, uint16_t* __restrict__ kbuf,
                uint16_t* __restrict__ vtbuf) {
    __shared__ __align__(16) uint16_t Alds[128 * 72];
    __shared__ __align__(16) uint16_t Blds[192 * 72];
    const int tid  = threadIdx.x;
    const int lane = tid & 63;
    const int wv   = tid >> 6;       // 0..7
    const int wm   = wv >> 2;        // 0..1
    const int wn   = wv & 3;         // 0..3
    const int quad = lane >> 4;
    const int l15  = lane & 15;
    const int m0   = blockIdx.x * 128;
    const int cb   = blockIdx.y;
    const int nbase = cb * 192;

    f32x4 acc[4][3];
#pragma unroll
    for (int a = 0; a < 4; a++)
#pragma unroll
        for (int b = 0; b < 3; b++) acc[a][b] = (f32x4)0.f;

    for (int k0 = 0; k0 < 192; k0 += 64) {
        __syncthreads();
        // stage A: 128x64 fp32 -> bf16 LDS
#pragma unroll
        for (int p = 0; p < 4; p++) {
            int f = tid + p * 512;                 // 2048 float4
            int row = f >> 4, c4 = f & 15;
            const float4 v = *reinterpret_cast<const float4*>(
                x + (int64_t)(m0 + row) * 192 + k0 + c4 * 4);
            ushort4 s4;
            s4.x = f2bf(v.x); s4.y = f2bf(v.y); s4.z = f2bf(v.z); s4.w = f2bf(v.w);
            *reinterpret_cast<ushort4*>(&Alds[row * 72 + c4 * 4]) = s4;
        }
        // stage B: 192x64 bf16
#pragma unroll
        for (int p = 0; p < 3; p++) {
            int u = tid + p * 512;                 // 1536 ushort8
            int row = u >> 3, c8 = u & 7;
            uint4 w = *reinterpret_cast<const uint4*>(
                wq + (int64_t)(nbase + row) * 192 + k0 + c8 * 8);
            *reinterpret_cast<uint4*>(&Blds[row * 72 + c8 * 8]) = w;
        }
        __syncthreads();
#pragma unroll
        for (int ks = 0; ks < 2; ks++) {
            bf16x8 af[4], bfr[3];
#pragma unroll
            for (int mt = 0; mt < 4; mt++)
                af[mt] = *reinterpret_cast<const bf16x8*>(
                    &Alds[(wm * 64 + mt * 16 + l15) * 72 + ks * 32 + quad * 8]);
#pragma unroll
            for (int nt = 0; nt < 3; nt++)
                bfr[nt] = *reinterpret_cast<const bf16x8*>(
                    &Blds[(wn * 48 + nt * 16 + l15) * 72 + ks * 32 + quad * 8]);
#pragma unroll
            for (int mt = 0; mt < 4; mt++)
#pragma unroll
                for (int nt = 0; nt < 3; nt++)
                    acc[mt][nt] = __builtin_amdgcn_mfma_f32_16x16x32_bf16(
                        af[mt], bfr[nt], acc[mt][nt], 0, 0, 0);
        }
    }
    const float scale = 0.17677669529663687f;      // 32^-0.5
#pragma unroll
    for (int mt = 0; mt < 4; mt++)
#pragma unroll
        for (int nt = 0; nt < 3; nt++)
#pragma unroll
            for (int r = 0; r < 4; r++) {
                int m   = m0 + wm * 64 + mt * 16 + quad * 4 + r;
                int col = wn * 48 + nt * 16 + l15;       // 0..191
                int b = m >> 8, pos = m & 255;
                int h = col >> 5, d = col & 31;
                float v = acc[mt][nt][r];
                int64_t bh = (int64_t)b * H_ + h;
                if (cb == 0)      qbuf [(bh * N_ + pos) * D_ + d] = f2bf(v * scale);
                else if (cb == 1) kbuf [(bh * N_ + pos) * D_ + d] = f2bf(v);
                else              vtbuf[(bh * D_ + d) * N_ + pos] = f2bf(v);
            }
}

// ---------------- kernel B: attention per (b,h) ------------------------------
// grid 3072, block 256 (4 waves, each owns 64 q-rows). No __syncthreads needed.
__global__ __launch_bounds__(256, 2)
void attn_kernel(const uint16_t* __restrict__ qbuf, const uint16_t* __restrict__ kbuf,
                 const uint16_t* __restrict__ vtbuf, const uint16_t* __restrict__ sel,
                 uint16_t* __restrict__ aout) {
    __shared__ __align__(16) uint16_t Plds[4 * 64 * 72];   // per-wave P strips
    const int bi = blockIdx.x;
    const int h  = bi % 6;
    const int g  = (bi / 6) & 7;
    const int w  = bi / 48;                 // same-w blocks adjacent -> L2 locality
    const int b  = g * 64 + w;              // b % 64 == w  (matches reshape(8,64,...))
    const int tid  = threadIdx.x;
    const int lane = tid & 63;
    const int wv   = tid >> 6;
    const int quad = lane >> 4;
    const int l15  = lane & 15;
    const int i0   = wv * 64;
    const int64_t bh = (int64_t)b * H_ + h;
    const uint16_t* qB = qbuf  + bh * N_ * D_;
    const uint16_t* kB = kbuf  + bh * N_ * D_;
    const uint16_t* vB = vtbuf + bh * D_ * N_;
    const uint16_t* sB = sel   + (int64_t)w * N_ * N_;
    uint16_t* Pw = &Plds[wv * 64 * 72];

    // Q fragments (A-layout: m=lane&15, k=quad*8+j), q pre-scaled in kernel A
    bf16x8 qf[4];
#pragma unroll
    for (int mt = 0; mt < 4; mt++)
        qf[mt] = ld_bf8(&qB[(i0 + mt * 16 + l15) * D_ + quad * 8]);

    f32x4 oacc[4][2];
    f32x4 lacc[4];
#pragma unroll
    for (int mt = 0; mt < 4; mt++) {
        oacc[mt][0] = (f32x4)0.f; oacc[mt][1] = (f32x4)0.f; lacc[mt] = (f32x4)0.f;
    }
    bf16x8 ones;
#pragma unroll
    for (int e = 0; e < 8; e++) ones[e] = (short)0x3F80;   // bf16 1.0

    for (int jc = 0; jc < 4; jc++) {
        const int j0 = jc * 64;
        // K fragments (B-layout: n=lane&15 -> j, k=quad*8+j -> d)
        bf16x8 kf[4];
#pragma unroll
        for (int nt = 0; nt < 4; nt++)
            kf[nt] = ld_bf8(&kB[(j0 + nt * 16 + l15) * D_ + quad * 8]);

        f32x4 sacc[4][4];
#pragma unroll
        for (int mt = 0; mt < 4; mt++)
#pragma unroll
            for (int nt = 0; nt < 4; nt++) sacc[mt][nt] = (f32x4)0.f;
#pragma unroll
        for (int mt = 0; mt < 4; mt++)
#pragma unroll
            for (int nt = 0; nt < 4; nt++)
                sacc[mt][nt] = __builtin_amdgcn_mfma_f32_16x16x32_bf16(
                    qf[mt], kf[nt], sacc[mt][nt], 0, 0, 0);

        // P = exp(S)  (no max subtraction: |S| tiny; clamp for safety) -> LDS bf16
#pragma unroll
        for (int mt = 0; mt < 4; mt++)
#pragma unroll
            for (int nt = 0; nt < 4; nt++)
#pragma unroll
                for (int r = 0; r < 4; r++) {
                    float e = __expf(fminf(sacc[mt][nt][r], 80.f));
                    Pw[(mt * 16 + quad * 4 + r) * 72 + nt * 16 + l15] = f2bf(e);
                }

        // V fragments from vT (B-layout: n=lane&15 -> d, k -> j)
        bf16x8 vf[2][2];
#pragma unroll
        for (int ks = 0; ks < 2; ks++)
#pragma unroll
            for (int nt = 0; nt < 2; nt++)
                vf[ks][nt] = ld_bf8(&vB[(nt * 16 + l15) * N_ + j0 + ks * 32 + quad * 8]);

        // PV + ones-MFMA row-sum, with mask AND applied on P fragments
#pragma unroll
        for (int ks = 0; ks < 2; ks++)
#pragma unroll
            for (int mt = 0; mt < 4; mt++) {
                uint4 p = *reinterpret_cast<const uint4*>(
                    &Pw[(mt * 16 + l15) * 72 + ks * 32 + quad * 8]);
                const uint4 s = *reinterpret_cast<const uint4*>(
                    &sB[(int64_t)(i0 + mt * 16 + l15) * N_ + j0 + ks * 32 + quad * 8]);
                p.x &= s.x; p.y &= s.y; p.z &= s.z; p.w &= s.w;
                bf16x8 pa = __builtin_bit_cast(bf16x8, p);
                oacc[mt][0] = __builtin_amdgcn_mfma_f32_16x16x32_bf16(pa, vf[ks][0], oacc[mt][0], 0, 0, 0);
                oacc[mt][1] = __builtin_amdgcn_mfma_f32_16x16x32_bf16(pa, vf[ks][1], oacc[mt][1], 0, 0, 0);
                lacc[mt]    = __builtin_amdgcn_mfma_f32_16x16x32_bf16(pa, ones,      lacc[mt],    0, 0, 0);
            }
    }

    // normalize (l is in the same C-layout as O: every lane holds its row's sum)
#pragma unroll
    for (int mt = 0; mt < 4; mt++)
#pragma unroll
        for (int r = 0; r < 4; r++) {
            float inv = 1.0f / lacc[mt][r];
            int i = i0 + mt * 16 + quad * 4 + r;
#pragma unroll
            for (int nt = 0; nt < 2; nt++) {
                float v = oacc[mt][nt][r] * inv;
                aout[((int64_t)b * N_ + i) * C_ + h * 32 + nt * 16 + l15] = f2bf(v);
            }
        }
}

// ---------------- kernel C: out = attn_out @ Wproj^T + b ---------------------
// grid 1024, block 512
__global__ __launch_bounds__(512, 2)
void proj_kernel(const uint16_t* __restrict__ a, const uint16_t* __restrict__ wp,
                 const float* __restrict__ bias, float* __restrict__ out) {
    __shared__ __align__(16) uint16_t Alds[128 * 72];
    __shared__ __align__(16) uint16_t Blds[192 * 72];
    const int tid  = threadIdx.x;
    const int lane = tid & 63;
    const int wv   = tid >> 6;
    const int wm   = wv >> 2;
    const int wn   = wv & 3;
    const int quad = lane >> 4;
    const int l15  = lane & 15;
    const int m0   = blockIdx.x * 128;

    f32x4 acc[4][3];
#pragma unroll
    for (int x = 0; x < 4; x++)
#pragma unroll
        for (int y = 0; y < 3; y++) acc[x][y] = (f32x4)0.f;

    for (int k0 = 0; k0 < 192; k0 += 64) {
        __syncthreads();
#pragma unroll
        for (int p = 0; p < 2; p++) {
            int u = tid + p * 512;                 // 1024 ushort8
            int row = u >> 3, c8 = u & 7;
            uint4 v = *reinterpret_cast<const uint4*>(
                a + (int64_t)(m0 + row) * 192 + k0 + c8 * 8);
            *reinterpret_cast<uint4*>(&Alds[row * 72 + c8 * 8]) = v;
        }
#pragma unroll
        for (int p = 0; p < 3; p++) {
            int u = tid + p * 512;                 // 1536 ushort8
            int row = u >> 3, c8 = u & 7;
            uint4 v = *reinterpret_cast<const uint4*>(
                wp + (int64_t)row * 192 + k0 + c8 * 8);
            *reinterpret_cast<uint4*>(&Blds[row * 72 + c8 * 8]) = v;
        }
        __syncthreads();
#pragma unroll
        for (int ks = 0; ks < 2; ks++) {
            bf16x8 af[4], bfr[3];
#pragma unroll
            for (int mt = 0; mt < 4; mt++)
                af[mt] = *reinterpret_cast<const bf16x8*>(
                    &Alds[(wm * 64 + mt * 16 + l15) * 72 + ks * 32 + quad * 8]);
#pragma unroll
            for (int nt = 0; nt < 3; nt++)
                bfr[nt] = *reinterpret_cast<const bf16x8*>(
                    &Blds[(wn * 48 + nt * 16 + l15) * 72 + ks * 32 + quad * 8]);
#pragma unroll
            for (int mt = 0; mt < 4; mt++)
#pragma unroll
                for (int nt = 0; nt < 3; nt++)
                    acc[mt][nt] = __builtin_amdgcn_mfma_f32_16x16x32_bf16(
                        af[mt], bfr[nt], acc[mt][nt], 0, 0, 0);
        }
    }
    float bv[3];
#pragma unroll
    for (int nt = 0; nt < 3; nt++) bv[nt] = bias[wn * 48 + nt * 16 + l15];
#pragma unroll
    for (int mt = 0; mt < 4; mt++)
#pragma unroll
        for (int r = 0; r < 4; r++) {
            int m = m0 + wm * 64 + mt * 16 + quad * 4 + r;
#pragma unroll
            for (int nt = 0; nt < 3; nt++) {
                int col = wn * 48 + nt * 16 + l15;
                out[(int64_t)m * 192 + col] = acc[mt][nt][r] + bv[nt];
            }
        }
}

extern "C" void kernel_launch(void* const* d_in, const int* in_sizes, int n_in,
                              void* d_out, int out_size, void* d_ws, size_t ws_size,
                              hipStream_t stream) {
    const float* x     = (const float*)d_in[0];
    const float* mask  = (const float*)d_in[1];
    const float* wqkv  = (const float*)d_in[2];
    const float* wproj = (const float*)d_in[3];
    const float* bproj = (const float*)d_in[4];
    float* out = (float*)d_out;

    // q,k (bf16) live in d_out (exactly 2 x 50331648 B = out bytes); overwritten by proj at the end.
    uint16_t* qbuf = (uint16_t*)d_out;
    uint16_t* kbuf = qbuf + 25165824;
    char* ws = (char*)d_ws;
    uint16_t* vtbuf = (uint16_t*)(ws);                 // 50331648 B
    uint16_t* aout  = (uint16_t*)(ws + 50331648);      // 50331648 B
    uint16_t* sel   = (uint16_t*)(ws + 100663296);     // 8388608 B
    uint16_t* wq_bf = (uint16_t*)(ws + 109051904);     // 221184 B
    uint16_t* wp_bf = (uint16_t*)(ws + 109273088);     // 73728 B
    // total ws use: ~109.3 MB

    prep_kernel<<<4096, 256, 0, stream>>>(mask, wqkv, wproj, sel, wq_bf, wp_bf);
    qkv_kernel<<<dim3(1024, 3), 512, 0, stream>>>(x, wq_bf, qbuf, kbuf, vtbuf);
    attn_kernel<<<3072, 256, 0, stream>>>(qbuf, kbuf, vtbuf, sel, aout);
    proj_kernel<<<1024, 512, 0, stream>>>(aout, wp_bf, bproj, out);
}

// Round 2
// 383.218 us; speedup vs baseline: 1.1781x; 1.1781x over previous
//
#include <hip/hip_runtime.h>
#include <stdint.h>

typedef short bf16x8 __attribute__((ext_vector_type(8)));
typedef float f32x4 __attribute__((ext_vector_type(4)));

#define B_   512
#define N_   256
#define C_   192
#define H_   6
#define D_   32
#define NW_  64

__device__ __forceinline__ uint16_t f2bf(float f) {
    uint32_t u = __builtin_bit_cast(uint32_t, f);
    u += 0x7FFFu + ((u >> 16) & 1u);
    return (uint16_t)(u >> 16);
}

__device__ __forceinline__ bf16x8 ld_bf8(const uint16_t* p) {
    uint4 u = *reinterpret_cast<const uint4*>(p);
    return __builtin_bit_cast(bf16x8, u);
}

// ---------------- prep: mask -> AND-selector, weights -> bf16 ----------------
__global__ void prep_kernel(const float* __restrict__ mask,
                            const float* __restrict__ wqkv,
                            const float* __restrict__ wproj,
                            uint16_t* __restrict__ sel,
                            uint16_t* __restrict__ wqkv_bf,
                            uint16_t* __restrict__ wproj_bf) {
    const int64_t NSEL = (int64_t)NW_ * N_ * N_;       // 4194304
    const int64_t NWQ  = 3 * C_ * C_;                  // 110592
    const int64_t NWP  = (int64_t)C_ * C_;             // 36864
    int64_t i = (int64_t)blockIdx.x * blockDim.x + threadIdx.x;
    int64_t stride = (int64_t)gridDim.x * blockDim.x;
    for (; i < NSEL + NWQ + NWP; i += stride) {
        if (i < NSEL) {
            sel[i] = (mask[i] == 0.0f) ? 0xFFFFu : 0u;   // exp(0)=1, exp(-inf)=0
        } else if (i < NSEL + NWQ) {
            int64_t j = i - NSEL;
            wqkv_bf[j] = f2bf(wqkv[j]);
        } else {
            int64_t j = i - NSEL - NWQ;
            wproj_bf[j] = f2bf(wproj[j]);
        }
    }
}

// ---------------- kernel A: qkv = x @ Wqkv^T, single pass over x ------------
// grid 1024, block 512. Stage x-tile (128x192 bf16) once; loop cb in {q,k,v}.
// q/k use swapped MFMA operands (A=W, B=x) so each lane holds 4 consecutive
// c values -> 8-byte packed stores. v uses A=x, B=W so each lane holds 4
// consecutive pos values -> 8-byte packed stores into vT.
#define SA 200   // x LDS stride (u16): 100 dwords -> lane*4 % 32 -> 2-way, free
#define SB 72    // W LDS stride (u16)
__global__ __launch_bounds__(512, 4)
void qkv_kernel(const float* __restrict__ x, const uint16_t* __restrict__ wq,
                uint16_t* __restrict__ qbuf, uint16_t* __restrict__ kbuf,
                uint16_t* __restrict__ vtbuf) {
    __shared__ __align__(16) uint16_t Alds[128 * SA];   // 51200 B
    __shared__ __align__(16) uint16_t Blds[192 * SB];   // 27648 B
    const int tid  = threadIdx.x;
    const int lane = tid & 63;
    const int wv   = tid >> 6;       // 0..7
    const int wrow = wv >> 2;        // 0..1 : which 64 pos-rows
    const int wcol = wv & 3;         // 0..3 : which 48 c-cols
    const int quad = lane >> 4;
    const int l15  = lane & 15;
    const int m0   = blockIdx.x * 128;

    // stage A once: 128x192 fp32 -> bf16 (6144 float4, 12 per thread)
#pragma unroll
    for (int p = 0; p < 12; p++) {
        int f = p * 512 + tid;
        int row = f / 48, c4 = f % 48;
        const float4 v = *reinterpret_cast<const float4*>(
            x + (int64_t)(m0 + row) * 192 + c4 * 4);
        ushort4 s4;
        s4.x = f2bf(v.x); s4.y = f2bf(v.y); s4.z = f2bf(v.z); s4.w = f2bf(v.w);
        *reinterpret_cast<ushort4*>(&Alds[row * SA + c4 * 4]) = s4;
    }

    const float scale = 0.17677669529663687f;      // 32^-0.5

    for (int cb = 0; cb < 3; cb++) {
        f32x4 acc[4][3];   // [x pos-tile][w c-tile]
#pragma unroll
        for (int i = 0; i < 4; i++)
#pragma unroll
            for (int j = 0; j < 3; j++) acc[i][j] = (f32x4)0.f;

        for (int k0 = 0; k0 < 192; k0 += 64) {
            __syncthreads();   // protect Blds readers of previous chunk / Alds writes
            // stage W slice: 192x64 bf16 (1536 uint4, 3 per thread)
#pragma unroll
            for (int p = 0; p < 3; p++) {
                int u = p * 512 + tid;
                int row = u >> 3, c8 = u & 7;
                uint4 w = *reinterpret_cast<const uint4*>(
                    wq + (int64_t)(cb * 192 + row) * 192 + k0 + c8 * 8);
                *reinterpret_cast<uint4*>(&Blds[row * SB + c8 * 8]) = w;
            }
            __syncthreads();
#pragma unroll
            for (int ks = 0; ks < 2; ks++) {
                bf16x8 xf[4], wf[3];
#pragma unroll
                for (int i = 0; i < 4; i++)
                    xf[i] = *reinterpret_cast<const bf16x8*>(
                        &Alds[(wrow * 64 + i * 16 + l15) * SA + k0 + ks * 32 + quad * 8]);
#pragma unroll
                for (int j = 0; j < 3; j++)
                    wf[j] = *reinterpret_cast<const bf16x8*>(
                        &Blds[(wcol * 48 + j * 16 + l15) * SB + ks * 32 + quad * 8]);
                if (cb < 2) {
#pragma unroll
                    for (int i = 0; i < 4; i++)
#pragma unroll
                        for (int j = 0; j < 3; j++)
                            acc[i][j] = __builtin_amdgcn_mfma_f32_16x16x32_bf16(
                                wf[j], xf[i], acc[i][j], 0, 0, 0);
                } else {
#pragma unroll
                    for (int i = 0; i < 4; i++)
#pragma unroll
                        for (int j = 0; j < 3; j++)
                            acc[i][j] = __builtin_amdgcn_mfma_f32_16x16x32_bf16(
                                xf[i], wf[j], acc[i][j], 0, 0, 0);
                }
            }
        }

        // epilogue: 8-byte packed stores
        if (cb < 2) {
            // lane dim = pos, reg dim = c (4 consecutive)
            uint16_t* dst = (cb == 0) ? qbuf : kbuf;
            const float sc = (cb == 0) ? scale : 1.0f;
#pragma unroll
            for (int i = 0; i < 4; i++) {
                int m = m0 + wrow * 64 + i * 16 + l15;
                int b = m >> 8, pos = m & 255;
#pragma unroll
                for (int j = 0; j < 3; j++) {
                    int cbase = wcol * 48 + j * 16 + quad * 4;
                    int h = cbase >> 5, d0 = cbase & 31;
                    int64_t bh = (int64_t)b * H_ + h;
                    ushort4 s;
                    s.x = f2bf(acc[i][j][0] * sc);
                    s.y = f2bf(acc[i][j][1] * sc);
                    s.z = f2bf(acc[i][j][2] * sc);
                    s.w = f2bf(acc[i][j][3] * sc);
                    *reinterpret_cast<ushort4*>(&dst[(bh * N_ + pos) * D_ + d0]) = s;
                }
            }
        } else {
            // lane dim = c, reg dim = pos (4 consecutive) -> vT rows
#pragma unroll
            for (int i = 0; i < 4; i++) {
                int m = m0 + wrow * 64 + i * 16 + quad * 4;
                int b = m >> 8, pos0 = m & 255;
#pragma unroll
                for (int j = 0; j < 3; j++) {
                    int c = wcol * 48 + j * 16 + l15;
                    int h = c >> 5, d = c & 31;
                    int64_t bh = (int64_t)b * H_ + h;
                    ushort4 s;
                    s.x = f2bf(acc[i][j][0]);
                    s.y = f2bf(acc[i][j][1]);
                    s.z = f2bf(acc[i][j][2]);
                    s.w = f2bf(acc[i][j][3]);
                    *reinterpret_cast<ushort4*>(&vtbuf[(bh * D_ + d) * N_ + pos0]) = s;
                }
            }
        }
    }
}

// ---------------- kernel B: attention per (b,h) ------------------------------
// grid 3072, block 256 (4 waves, each owns 64 q-rows). No __syncthreads needed.
__global__ __launch_bounds__(256, 2)
void attn_kernel(const uint16_t* __restrict__ qbuf, const uint16_t* __restrict__ kbuf,
                 const uint16_t* __restrict__ vtbuf, const uint16_t* __restrict__ sel,
                 uint16_t* __restrict__ aout) {
    __shared__ __align__(16) uint16_t Plds[4 * 64 * 72];   // per-wave P strips
    const int bi = blockIdx.x;
    const int h  = bi % 6;
    const int g  = (bi / 6) & 7;
    const int w  = bi / 48;                 // same-w blocks adjacent -> L2 locality
    const int b  = g * 64 + w;              // b % 64 == w  (matches reshape(8,64,...))
    const int tid  = threadIdx.x;
    const int lane = tid & 63;
    const int wv   = tid >> 6;
    const int quad = lane >> 4;
    const int l15  = lane & 15;
    const int i0   = wv * 64;
    const int64_t bh = (int64_t)b * H_ + h;
    const uint16_t* qB = qbuf  + bh * N_ * D_;
    const uint16_t* kB = kbuf  + bh * N_ * D_;
    const uint16_t* vB = vtbuf + bh * D_ * N_;
    const uint16_t* sB = sel   + (int64_t)w * N_ * N_;
    uint16_t* Pw = &Plds[wv * 64 * 72];

    // Q fragments (A-layout: m=lane&15, k=quad*8+j), q pre-scaled in kernel A
    bf16x8 qf[4];
#pragma unroll
    for (int mt = 0; mt < 4; mt++)
        qf[mt] = ld_bf8(&qB[(i0 + mt * 16 + l15) * D_ + quad * 8]);

    f32x4 oacc[4][2];
    f32x4 lacc[4];
#pragma unroll
    for (int mt = 0; mt < 4; mt++) {
        oacc[mt][0] = (f32x4)0.f; oacc[mt][1] = (f32x4)0.f; lacc[mt] = (f32x4)0.f;
    }
    bf16x8 ones;
#pragma unroll
    for (int e = 0; e < 8; e++) ones[e] = (short)0x3F80;   // bf16 1.0

    for (int jc = 0; jc < 4; jc++) {
        const int j0 = jc * 64;
        // K fragments (B-layout: n=lane&15 -> j, k=quad*8+j -> d)
        bf16x8 kf[4];
#pragma unroll
        for (int nt = 0; nt < 4; nt++)
            kf[nt] = ld_bf8(&kB[(j0 + nt * 16 + l15) * D_ + quad * 8]);

        f32x4 sacc[4][4];
#pragma unroll
        for (int mt = 0; mt < 4; mt++)
#pragma unroll
            for (int nt = 0; nt < 4; nt++) sacc[mt][nt] = (f32x4)0.f;
#pragma unroll
        for (int mt = 0; mt < 4; mt++)
#pragma unroll
            for (int nt = 0; nt < 4; nt++)
                sacc[mt][nt] = __builtin_amdgcn_mfma_f32_16x16x32_bf16(
                    qf[mt], kf[nt], sacc[mt][nt], 0, 0, 0);

        // P = exp(S)  (no max subtraction: |S| tiny; clamp for safety) -> LDS bf16
#pragma unroll
        for (int mt = 0; mt < 4; mt++)
#pragma unroll
            for (int nt = 0; nt < 4; nt++)
#pragma unroll
                for (int r = 0; r < 4; r++) {
                    float e = __expf(fminf(sacc[mt][nt][r], 80.f));
                    Pw[(mt * 16 + quad * 4 + r) * 72 + nt * 16 + l15] = f2bf(e);
                }

        // V fragments from vT (B-layout: n=lane&15 -> d, k -> j)
        bf16x8 vf[2][2];
#pragma unroll
        for (int ks = 0; ks < 2; ks++)
#pragma unroll
            for (int nt = 0; nt < 2; nt++)
                vf[ks][nt] = ld_bf8(&vB[(nt * 16 + l15) * N_ + j0 + ks * 32 + quad * 8]);

        // PV + ones-MFMA row-sum, with mask AND applied on P fragments
#pragma unroll
        for (int ks = 0; ks < 2; ks++)
#pragma unroll
            for (int mt = 0; mt < 4; mt++) {
                uint4 p = *reinterpret_cast<const uint4*>(
                    &Pw[(mt * 16 + l15) * 72 + ks * 32 + quad * 8]);
                const uint4 s = *reinterpret_cast<const uint4*>(
                    &sB[(int64_t)(i0 + mt * 16 + l15) * N_ + j0 + ks * 32 + quad * 8]);
                p.x &= s.x; p.y &= s.y; p.z &= s.z; p.w &= s.w;
                bf16x8 pa = __builtin_bit_cast(bf16x8, p);
                oacc[mt][0] = __builtin_amdgcn_mfma_f32_16x16x32_bf16(pa, vf[ks][0], oacc[mt][0], 0, 0, 0);
                oacc[mt][1] = __builtin_amdgcn_mfma_f32_16x16x32_bf16(pa, vf[ks][1], oacc[mt][1], 0, 0, 0);
                lacc[mt]    = __builtin_amdgcn_mfma_f32_16x16x32_bf16(pa, ones,      lacc[mt],    0, 0, 0);
            }
    }

    // normalize (l is in the same C-layout as O: every lane holds its row's sum)
#pragma unroll
    for (int mt = 0; mt < 4; mt++)
#pragma unroll
        for (int r = 0; r < 4; r++) {
            float inv = 1.0f / lacc[mt][r];
            int i = i0 + mt * 16 + quad * 4 + r;
#pragma unroll
            for (int nt = 0; nt < 2; nt++) {
                float v = oacc[mt][nt][r] * inv;
                aout[((int64_t)b * N_ + i) * C_ + h * 32 + nt * 16 + l15] = f2bf(v);
            }
        }
}

// ---------------- kernel C: out = attn_out @ Wproj^T + b ---------------------
// grid 1024, block 512
__global__ __launch_bounds__(512, 2)
void proj_kernel(const uint16_t* __restrict__ a, const uint16_t* __restrict__ wp,
                 const float* __restrict__ bias, float* __restrict__ out) {
    __shared__ __align__(16) uint16_t Alds[128 * 72];
    __shared__ __align__(16) uint16_t Blds[192 * 72];
    const int tid  = threadIdx.x;
    const int lane = tid & 63;
    const int wv   = tid >> 6;
    const int wm   = wv >> 2;
    const int wn   = wv & 3;
    const int quad = lane >> 4;
    const int l15  = lane & 15;
    const int m0   = blockIdx.x * 128;

    f32x4 acc[4][3];
#pragma unroll
    for (int x = 0; x < 4; x++)
#pragma unroll
        for (int y = 0; y < 3; y++) acc[x][y] = (f32x4)0.f;

    for (int k0 = 0; k0 < 192; k0 += 64) {
        __syncthreads();
#pragma unroll
        for (int p = 0; p < 2; p++) {
            int u = tid + p * 512;                 // 1024 ushort8
            int row = u >> 3, c8 = u & 7;
            uint4 v = *reinterpret_cast<const uint4*>(
                a + (int64_t)(m0 + row) * 192 + k0 + c8 * 8);
            *reinterpret_cast<uint4*>(&Alds[row * 72 + c8 * 8]) = v;
        }
#pragma unroll
        for (int p = 0; p < 3; p++) {
            int u = tid + p * 512;                 // 1536 ushort8
            int row = u >> 3, c8 = u & 7;
            uint4 v = *reinterpret_cast<const uint4*>(
                wp + (int64_t)row * 192 + k0 + c8 * 8);
            *reinterpret_cast<uint4*>(&Blds[row * 72 + c8 * 8]) = v;
        }
        __syncthreads();
#pragma unroll
        for (int ks = 0; ks < 2; ks++) {
            bf16x8 af[4], bfr[3];
#pragma unroll
            for (int mt = 0; mt < 4; mt++)
                af[mt] = *reinterpret_cast<const bf16x8*>(
                    &Alds[(wm * 64 + mt * 16 + l15) * 72 + ks * 32 + quad * 8]);
#pragma unroll
            for (int nt = 0; nt < 3; nt++)
                bfr[nt] = *reinterpret_cast<const bf16x8*>(
                    &Blds[(wn * 48 + nt * 16 + l15) * 72 + ks * 32 + quad * 8]);
#pragma unroll
            for (int mt = 0; mt < 4; mt++)
#pragma unroll
                for (int nt = 0; nt < 3; nt++)
                    acc[mt][nt] = __builtin_amdgcn_mfma_f32_16x16x32_bf16(
                        af[mt], bfr[nt], acc[mt][nt], 0, 0, 0);
        }
    }
    float bv[3];
#pragma unroll
    for (int nt = 0; nt < 3; nt++) bv[nt] = bias[wn * 48 + nt * 16 + l15];
#pragma unroll
    for (int mt = 0; mt < 4; mt++)
#pragma unroll
        for (int r = 0; r < 4; r++) {
            int m = m0 + wm * 64 + mt * 16 + quad * 4 + r;
#pragma unroll
            for (int nt = 0; nt < 3; nt++) {
                int col = wn * 48 + nt * 16 + l15;
                out[(int64_t)m * 192 + col] = acc[mt][nt][r] + bv[nt];
            }
        }
}

extern "C" void kernel_launch(void* const* d_in, const int* in_sizes, int n_in,
                              void* d_out, int out_size, void* d_ws, size_t ws_size,
                              hipStream_t stream) {
    const float* x     = (const float*)d_in[0];
    const float* mask  = (const float*)d_in[1];
    const float* wqkv  = (const float*)d_in[2];
    const float* wproj = (const float*)d_in[3];
    const float* bproj = (const float*)d_in[4];
    float* out = (float*)d_out;

    // q,k (bf16) live in d_out (exactly 2 x 50331648 B = out bytes); overwritten by proj at the end.
    uint16_t* qbuf = (uint16_t*)d_out;
    uint16_t* kbuf = qbuf + 25165824;
    char* ws = (char*)d_ws;
    uint16_t* vtbuf = (uint16_t*)(ws);                 // 50331648 B
    uint16_t* aout  = (uint16_t*)(ws + 50331648);      // 50331648 B
    uint16_t* sel   = (uint16_t*)(ws + 100663296);     // 8388608 B
    uint16_t* wq_bf = (uint16_t*)(ws + 109051904);     // 221184 B
    uint16_t* wp_bf = (uint16_t*)(ws + 109273088);     // 73728 B
    // total ws use: ~109.3 MB

    prep_kernel<<<4096, 256, 0, stream>>>(mask, wqkv, wproj, sel, wq_bf, wp_bf);
    qkv_kernel<<<1024, 512, 0, stream>>>(x, wq_bf, qbuf, kbuf, vtbuf);
    attn_kernel<<<3072, 256, 0, stream>>>(qbuf, kbuf, vtbuf, sel, aout);
    proj_kernel<<<1024, 512, 0, stream>>>(aout, wp_bf, bproj, out);
}

// Round 4
// 356.044 us; speedup vs baseline: 1.2680x; 1.0763x over previous
//
#include <hip/hip_runtime.h>
#include <hip/hip_bf16.h>
#include <stdint.h>

typedef short bf16x8 __attribute__((ext_vector_type(8)));
typedef float f32x4 __attribute__((ext_vector_type(4)));

#define B_   512
#define N_   256
#define C_   192
#define H_   6
#define D_   32
#define NW_  64

__device__ __forceinline__ uint16_t f2bf(float f) {
    uint32_t u = __builtin_bit_cast(uint32_t, f);
    u += 0x7FFFu + ((u >> 16) & 1u);
    return (uint16_t)(u >> 16);
}

// packed 2xfp32 -> 2xbf16 (v_cvt_pk_bf16_f32 on gfx950)
__device__ __forceinline__ uint32_t pk_bf16(float a, float b) {
    float2 t; t.x = a; t.y = b;
    __hip_bfloat162 h = __float22bfloat162_rn(t);
    uint32_t u;
    __builtin_memcpy(&u, &h, 4);
    return u;
}

__device__ __forceinline__ bf16x8 ld_bf8(const uint16_t* p) {
    uint4 u = *reinterpret_cast<const uint4*>(p);
    return __builtin_bit_cast(bf16x8, u);
}

// ---------------- prep: mask -> AND-selector, weights -> bf16 ----------------
__global__ void prep_kernel(const float* __restrict__ mask,
                            const float* __restrict__ wqkv,
                            const float* __restrict__ wproj,
                            uint16_t* __restrict__ sel,
                            uint16_t* __restrict__ wqkv_bf,
                            uint16_t* __restrict__ wproj_bf) {
    const int64_t NSEL = (int64_t)NW_ * N_ * N_;       // 4194304
    const int64_t NWQ  = 3 * C_ * C_;                  // 110592
    const int64_t NWP  = (int64_t)C_ * C_;             // 36864
    int64_t i = (int64_t)blockIdx.x * blockDim.x + threadIdx.x;
    int64_t stride = (int64_t)gridDim.x * blockDim.x;
    for (; i < NSEL + NWQ + NWP; i += stride) {
        if (i < NSEL) {
            sel[i] = (mask[i] == 0.0f) ? 0xFFFFu : 0u;   // exp(0)=1, exp(-inf)=0
        } else if (i < NSEL + NWQ) {
            int64_t j = i - NSEL;
            wqkv_bf[j] = f2bf(wqkv[j]);
        } else {
            int64_t j = i - NSEL - NWQ;
            wproj_bf[j] = f2bf(wproj[j]);
        }
    }
}

// ---------------- kernel A: qkv = x @ Wqkv^T, single pass over x ------------
#define SA 200   // x LDS stride (u16)
#define SB 72    // W LDS stride (u16)
__global__ __launch_bounds__(512, 4)
void qkv_kernel(const float* __restrict__ x, const uint16_t* __restrict__ wq,
                uint16_t* __restrict__ qbuf, uint16_t* __restrict__ kbuf,
                uint16_t* __restrict__ vtbuf) {
    __shared__ __align__(16) uint16_t Alds[128 * SA];   // 51200 B
    __shared__ __align__(16) uint16_t Blds[192 * SB];   // 27648 B
    const int tid  = threadIdx.x;
    const int lane = tid & 63;
    const int wv   = tid >> 6;       // 0..7
    const int wrow = wv >> 2;        // 0..1 : which 64 pos-rows
    const int wcol = wv & 3;         // 0..3 : which 48 c-cols
    const int quad = lane >> 4;
    const int l15  = lane & 15;
    const int m0   = blockIdx.x * 128;

    // stage A once: 128x192 fp32 -> bf16 (6144 float4, 12 per thread)
#pragma unroll
    for (int p = 0; p < 12; p++) {
        int f = p * 512 + tid;
        int row = f / 48, c4 = f % 48;
        const float4 v = *reinterpret_cast<const float4*>(
            x + (int64_t)(m0 + row) * 192 + c4 * 4);
        uint2 d;
        d.x = pk_bf16(v.x, v.y);
        d.y = pk_bf16(v.z, v.w);
        *reinterpret_cast<uint2*>(&Alds[row * SA + c4 * 4]) = d;
    }

    const float scale = 0.17677669529663687f;      // 32^-0.5

    for (int cb = 0; cb < 3; cb++) {
        f32x4 acc[4][3];   // [x pos-tile][w c-tile]
#pragma unroll
        for (int i = 0; i < 4; i++)
#pragma unroll
            for (int j = 0; j < 3; j++) acc[i][j] = (f32x4)0.f;

        for (int k0 = 0; k0 < 192; k0 += 64) {
            __syncthreads();
#pragma unroll
            for (int p = 0; p < 3; p++) {
                int u = p * 512 + tid;
                int row = u >> 3, c8 = u & 7;
                uint4 w = *reinterpret_cast<const uint4*>(
                    wq + (int64_t)(cb * 192 + row) * 192 + k0 + c8 * 8);
                *reinterpret_cast<uint4*>(&Blds[row * SB + c8 * 8]) = w;
            }
            __syncthreads();
#pragma unroll
            for (int ks = 0; ks < 2; ks++) {
                bf16x8 xf[4], wf[3];
#pragma unroll
                for (int i = 0; i < 4; i++)
                    xf[i] = *reinterpret_cast<const bf16x8*>(
                        &Alds[(wrow * 64 + i * 16 + l15) * SA + k0 + ks * 32 + quad * 8]);
#pragma unroll
                for (int j = 0; j < 3; j++)
                    wf[j] = *reinterpret_cast<const bf16x8*>(
                        &Blds[(wcol * 48 + j * 16 + l15) * SB + ks * 32 + quad * 8]);
                if (cb < 2) {
#pragma unroll
                    for (int i = 0; i < 4; i++)
#pragma unroll
                        for (int j = 0; j < 3; j++)
                            acc[i][j] = __builtin_amdgcn_mfma_f32_16x16x32_bf16(
                                wf[j], xf[i], acc[i][j], 0, 0, 0);
                } else {
#pragma unroll
                    for (int i = 0; i < 4; i++)
#pragma unroll
                        for (int j = 0; j < 3; j++)
                            acc[i][j] = __builtin_amdgcn_mfma_f32_16x16x32_bf16(
                                xf[i], wf[j], acc[i][j], 0, 0, 0);
                }
            }
        }

        // epilogue: 8-byte packed stores
        if (cb < 2) {
            // lane dim = pos, reg dim = c (4 consecutive)
            uint16_t* dst = (cb == 0) ? qbuf : kbuf;
            const float sc = (cb == 0) ? scale : 1.0f;
#pragma unroll
            for (int i = 0; i < 4; i++) {
                int m = m0 + wrow * 64 + i * 16 + l15;
                int b = m >> 8, pos = m & 255;
#pragma unroll
                for (int j = 0; j < 3; j++) {
                    int cbase = wcol * 48 + j * 16 + quad * 4;
                    int h = cbase >> 5, d0 = cbase & 31;
                    int64_t bh = (int64_t)b * H_ + h;
                    uint2 s;
                    s.x = pk_bf16(acc[i][j][0] * sc, acc[i][j][1] * sc);
                    s.y = pk_bf16(acc[i][j][2] * sc, acc[i][j][3] * sc);
                    *reinterpret_cast<uint2*>(&dst[(bh * N_ + pos) * D_ + d0]) = s;
                }
            }
        } else {
            // lane dim = c, reg dim = pos (4 consecutive) -> vT rows
#pragma unroll
            for (int i = 0; i < 4; i++) {
                int m = m0 + wrow * 64 + i * 16 + quad * 4;
                int b = m >> 8, pos0 = m & 255;
#pragma unroll
                for (int j = 0; j < 3; j++) {
                    int c = wcol * 48 + j * 16 + l15;
                    int h = c >> 5, d = c & 31;
                    int64_t bh = (int64_t)b * H_ + h;
                    uint2 s;
                    s.x = pk_bf16(acc[i][j][0], acc[i][j][1]);
                    s.y = pk_bf16(acc[i][j][2], acc[i][j][3]);
                    *reinterpret_cast<uint2*>(&vtbuf[(bh * D_ + d) * N_ + pos0]) = s;
                }
            }
        }
    }
}

// ---------------- kernel B: attention per (b,h) ------------------------------
// grid 3072, block 256 (4 waves, each owns 64 q-rows). No __syncthreads needed.
// S^T trick: QK^T computed with swapped operands so the C-layout gives each
// lane 4 CONSECUTIVE j for fixed i -> packed 8B LDS writes of P.
__global__ __launch_bounds__(256, 2)
void attn_kernel(const uint16_t* __restrict__ qbuf, const uint16_t* __restrict__ kbuf,
                 const uint16_t* __restrict__ vtbuf, const uint16_t* __restrict__ sel,
                 uint16_t* __restrict__ aout) {
    __shared__ __align__(16) uint16_t Plds[4 * 64 * 72];   // per-wave P strips
    const int bi = blockIdx.x;
    const int h  = bi % 6;
    const int g  = (bi / 6) & 7;
    const int w  = bi / 48;                 // same-w blocks adjacent -> L2 locality
    const int b  = g * 64 + w;              // b % 64 == w
    const int tid  = threadIdx.x;
    const int lane = tid & 63;
    const int wv   = tid >> 6;
    const int quad = lane >> 4;
    const int l15  = lane & 15;
    const int i0   = wv * 64;
    const int64_t bh = (int64_t)b * H_ + h;
    const uint16_t* qB = qbuf  + bh * N_ * D_;
    const uint16_t* kB = kbuf  + bh * N_ * D_;
    const uint16_t* vB = vtbuf + bh * D_ * N_;
    const uint16_t* sB = sel   + (int64_t)w * N_ * N_;
    uint16_t* Pw = &Plds[wv * 64 * 72];

    // Q fragments (used as B-operand: n=lane&15 -> i, k=quad*8+e -> d)
    bf16x8 qf[4];
#pragma unroll
    for (int it = 0; it < 4; it++)
        qf[it] = ld_bf8(&qB[(i0 + it * 16 + l15) * D_ + quad * 8]);

    f32x4 oacc[4][2];
    f32x4 lacc[4];
#pragma unroll
    for (int mt = 0; mt < 4; mt++) {
        oacc[mt][0] = (f32x4)0.f; oacc[mt][1] = (f32x4)0.f; lacc[mt] = (f32x4)0.f;
    }
    bf16x8 ones;
#pragma unroll
    for (int e = 0; e < 8; e++) ones[e] = (short)0x3F80;   // bf16 1.0

    for (int jc = 0; jc < 4; jc++) {
        const int j0 = jc * 64;
        // K fragments (used as A-operand: m=lane&15 -> j, k=quad*8+e -> d)
        bf16x8 kf[4];
#pragma unroll
        for (int jt = 0; jt < 4; jt++)
            kf[jt] = ld_bf8(&kB[(j0 + jt * 16 + l15) * D_ + quad * 8]);

        // S^T = K Q^T : D[j][i], C-layout col=i=lane&15, row=j=quad*4+r
        f32x4 sacc[4][4];   // [jt][it]
#pragma unroll
        for (int jt = 0; jt < 4; jt++)
#pragma unroll
            for (int it = 0; it < 4; it++) sacc[jt][it] = (f32x4)0.f;
#pragma unroll
        for (int jt = 0; jt < 4; jt++)
#pragma unroll
            for (int it = 0; it < 4; it++)
                sacc[jt][it] = __builtin_amdgcn_mfma_f32_16x16x32_bf16(
                    kf[jt], qf[it], sacc[jt][it], 0, 0, 0);

        // P^T -> P in LDS: lane holds 4 consecutive j for i=it*16+l15
        // -> one packed 8B write per (it,jt)
#pragma unroll
        for (int it = 0; it < 4; it++)
#pragma unroll
            for (int jt = 0; jt < 4; jt++) {
                f32x4 s = sacc[jt][it];
                uint2 d;
                d.x = pk_bf16(__expf(s[0]), __expf(s[1]));
                d.y = pk_bf16(__expf(s[2]), __expf(s[3]));
                *reinterpret_cast<uint2*>(
                    &Pw[(it * 16 + l15) * 72 + jt * 16 + quad * 4]) = d;
            }

        // V fragments from vT (B-layout: n=lane&15 -> d, k -> j)
        bf16x8 vf[2][2];
#pragma unroll
        for (int ks = 0; ks < 2; ks++)
#pragma unroll
            for (int nt = 0; nt < 2; nt++)
                vf[ks][nt] = ld_bf8(&vB[(nt * 16 + l15) * N_ + j0 + ks * 32 + quad * 8]);

        // PV + ones-MFMA row-sum, with mask AND applied on P fragments
#pragma unroll
        for (int ks = 0; ks < 2; ks++)
#pragma unroll
            for (int mt = 0; mt < 4; mt++) {
                uint4 p = *reinterpret_cast<const uint4*>(
                    &Pw[(mt * 16 + l15) * 72 + ks * 32 + quad * 8]);
                const uint4 s = *reinterpret_cast<const uint4*>(
                    &sB[(int64_t)(i0 + mt * 16 + l15) * N_ + j0 + ks * 32 + quad * 8]);
                p.x &= s.x; p.y &= s.y; p.z &= s.z; p.w &= s.w;
                bf16x8 pa = __builtin_bit_cast(bf16x8, p);
                oacc[mt][0] = __builtin_amdgcn_mfma_f32_16x16x32_bf16(pa, vf[ks][0], oacc[mt][0], 0, 0, 0);
                oacc[mt][1] = __builtin_amdgcn_mfma_f32_16x16x32_bf16(pa, vf[ks][1], oacc[mt][1], 0, 0, 0);
                lacc[mt]    = __builtin_amdgcn_mfma_f32_16x16x32_bf16(pa, ones,      lacc[mt],    0, 0, 0);
            }
    }

    // normalize (l is in the same C-layout as O: every lane holds its row's sum)
#pragma unroll
    for (int mt = 0; mt < 4; mt++)
#pragma unroll
        for (int r = 0; r < 4; r++) {
            float inv = 1.0f / lacc[mt][r];
            int i = i0 + mt * 16 + quad * 4 + r;
#pragma unroll
            for (int nt = 0; nt < 2; nt++) {
                float v = oacc[mt][nt][r] * inv;
                aout[((int64_t)b * N_ + i) * C_ + h * 32 + nt * 16 + l15] = f2bf(v);
            }
        }
}

// ---------------- kernel C: out = attn_out @ Wproj^T + b ---------------------
// grid 1024, block 512
__global__ __launch_bounds__(512, 2)
void proj_kernel(const uint16_t* __restrict__ a, const uint16_t* __restrict__ wp,
                 const float* __restrict__ bias, float* __restrict__ out) {
    __shared__ __align__(16) uint16_t Alds[128 * 72];
    __shared__ __align__(16) uint16_t Blds[192 * 72];
    const int tid  = threadIdx.x;
    const int lane = tid & 63;
    const int wv   = tid >> 6;
    const int wm   = wv >> 2;
    const int wn   = wv & 3;
    const int quad = lane >> 4;
    const int l15  = lane & 15;
    const int m0   = blockIdx.x * 128;

    f32x4 acc[4][3];
#pragma unroll
    for (int x = 0; x < 4; x++)
#pragma unroll
        for (int y = 0; y < 3; y++) acc[x][y] = (f32x4)0.f;

    for (int k0 = 0; k0 < 192; k0 += 64) {
        __syncthreads();
#pragma unroll
        for (int p = 0; p < 2; p++) {
            int u = tid + p * 512;                 // 1024 ushort8
            int row = u >> 3, c8 = u & 7;
            uint4 v = *reinterpret_cast<const uint4*>(
                a + (int64_t)(m0 + row) * 192 + k0 + c8 * 8);
            *reinterpret_cast<uint4*>(&Alds[row * 72 + c8 * 8]) = v;
        }
#pragma unroll
        for (int p = 0; p < 3; p++) {
            int u = tid + p * 512;                 // 1536 ushort8
            int row = u >> 3, c8 = u & 7;
            uint4 v = *reinterpret_cast<const uint4*>(
                wp + (int64_t)row * 192 + k0 + c8 * 8);
            *reinterpret_cast<uint4*>(&Blds[row * 72 + c8 * 8]) = v;
        }
        __syncthreads();
#pragma unroll
        for (int ks = 0; ks < 2; ks++) {
            bf16x8 af[4], bfr[3];
#pragma unroll
            for (int mt = 0; mt < 4; mt++)
                af[mt] = *reinterpret_cast<const bf16x8*>(
                    &Alds[(wm * 64 + mt * 16 + l15) * 72 + ks * 32 + quad * 8]);
#pragma unroll
            for (int nt = 0; nt < 3; nt++)
                bfr[nt] = *reinterpret_cast<const bf16x8*>(
                    &Blds[(wn * 48 + nt * 16 + l15) * 72 + ks * 32 + quad * 8]);
#pragma unroll
            for (int mt = 0; mt < 4; mt++)
#pragma unroll
                for (int nt = 0; nt < 3; nt++)
                    acc[mt][nt] = __builtin_amdgcn_mfma_f32_16x16x32_bf16(
                        af[mt], bfr[nt], acc[mt][nt], 0, 0, 0);
        }
    }
    float bv[3];
#pragma unroll
    for (int nt = 0; nt < 3; nt++) bv[nt] = bias[wn * 48 + nt * 16 + l15];
#pragma unroll
    for (int mt = 0; mt < 4; mt++)
#pragma unroll
        for (int r = 0; r < 4; r++) {
            int m = m0 + wm * 64 + mt * 16 + quad * 4 + r;
#pragma unroll
            for (int nt = 0; nt < 3; nt++) {
                int col = wn * 48 + nt * 16 + l15;
                out[(int64_t)m * 192 + col] = acc[mt][nt][r] + bv[nt];
            }
        }
}

extern "C" void kernel_launch(void* const* d_in, const int* in_sizes, int n_in,
                              void* d_out, int out_size, void* d_ws, size_t ws_size,
                              hipStream_t stream) {
    const float* x     = (const float*)d_in[0];
    const float* mask  = (const float*)d_in[1];
    const float* wqkv  = (const float*)d_in[2];
    const float* wproj = (const float*)d_in[3];
    const float* bproj = (const float*)d_in[4];
    float* out = (float*)d_out;

    // q,k (bf16) live in d_out (exactly 2 x 50331648 B = out bytes); overwritten by proj at the end.
    uint16_t* qbuf = (uint16_t*)d_out;
    uint16_t* kbuf = qbuf + 25165824;
    char* ws = (char*)d_ws;
    uint16_t* vtbuf = (uint16_t*)(ws);                 // 50331648 B
    uint16_t* aout  = (uint16_t*)(ws + 50331648);      // 50331648 B
    uint16_t* sel   = (uint16_t*)(ws + 100663296);     // 8388608 B
    uint16_t* wq_bf = (uint16_t*)(ws + 109051904);     // 221184 B
    uint16_t* wp_bf = (uint16_t*)(ws + 109273088);     // 73728 B

    prep_kernel<<<4096, 256, 0, stream>>>(mask, wqkv, wproj, sel, wq_bf, wp_bf);
    qkv_kernel<<<1024, 512, 0, stream>>>(x, wq_bf, qbuf, kbuf, vtbuf);
    attn_kernel<<<3072, 256, 0, stream>>>(qbuf, kbuf, vtbuf, sel, aout);
    proj_kernel<<<1024, 512, 0, stream>>>(aout, wp_bf, bproj, out);
}